// Round 21
// baseline (175.988 us; speedup 1.0000x reference)
//
#include <hip/hip_runtime.h>
#include <math.h>

#define NF 10
#define TLEN 480
#define NWIN 24
#define WLEN 20
#define HID 64
#define NPAIR 45
#define DIN 210
#define NG 14
#define GATES 192
#define FROW 212            // fp32 feat row length (53 float4)
#define XROW 484            // padded LDS row
#define NB 4096             // stats blocks (one per batch element)
#define NW2 16384
#define RBLK 512            // rec blocks (8 batch rows each)

typedef __attribute__((ext_vector_type(8))) short bf16x8;
typedef __attribute__((ext_vector_type(4))) float f32x4;

#define MFMA(a,b,c) __builtin_amdgcn_mfma_f32_16x16x32_bf16((a),(b),(c),0,0,0)

__device__ __forceinline__ int grp_of(int k){ return (k < 90) ? (k / 45) : 2 + (k - 90) / 10; }

__device__ __forceinline__ void split2(float x, short& hi, short& lo){
    unsigned u = __float_as_uint(x);
    hi = (short)(u >> 16);
    float hf = __uint_as_float(u & 0xffff0000u);
    lo = (short)(__float_as_uint(x - hf) >> 16);
}
__device__ __forceinline__ short bf16rne(float x){
    unsigned u = __float_as_uint(x);
    u += 0x7fffu + ((u >> 16) & 1u);
    return (short)(u >> 16);
}
__device__ __forceinline__ float sigm(float x){
    return __builtin_amdgcn_rcpf(1.f + __builtin_amdgcn_exp2f(x * -1.4426950408889634f));
}
__device__ __forceinline__ float tanhfast(float x){
    return 1.f - 2.f * __builtin_amdgcn_rcpf(1.f + __builtin_amdgcn_exp2f(x * 2.8853900817779268f));
}

// ---------------------------------------------------------------------------
// stats v9 (unchanged from R20, best measured ~70us)
// ---------------------------------------------------------------------------
__global__ __launch_bounds__(256)
void stats_kernel(const float* __restrict__ data, float* __restrict__ feat32,
                  float* __restrict__ part1, float* __restrict__ part2)
{
    __shared__ __align__(16) float xs[NF * XROW];   // 19.36 KB
    __shared__ float ts[NWIN][121];                 // 11.6 KB  (col j*10+f)
    __shared__ float sgs[NG], sgq[NG];
    int b = blockIdx.x, tid = threadIdx.x;
    const float* src = data + (size_t)b * (NF * TLEN);

    for (int q = tid; q < 1200; q += 256){
        int f = q / 120, r = q % 120;
        *(float4*)&xs[f * XROW + r * 4] = *(const float4*)&src[q * 4];
    }
    if (tid < NG){ sgs[tid] = 0.f; sgq[tid] = 0.f; }
    __syncthreads();   // S1: xs staged

    // ---- singles ----
    if (tid < 240){
        int f = tid / NWIN, t = tid % NWIN;
        const float* p = &xs[f * XROW + t * WLEN];
        float v[WLEN];
        {
            float4 a0 = *(const float4*)(p + 0);
            float4 a1 = *(const float4*)(p + 4);
            float4 a2 = *(const float4*)(p + 8);
            float4 a3 = *(const float4*)(p + 12);
            float4 a4 = *(const float4*)(p + 16);
            v[0]=a0.x; v[1]=a0.y; v[2]=a0.z; v[3]=a0.w;
            v[4]=a1.x; v[5]=a1.y; v[6]=a1.z; v[7]=a1.w;
            v[8]=a2.x; v[9]=a2.y; v[10]=a2.z; v[11]=a2.w;
            v[12]=a3.x; v[13]=a3.y; v[14]=a3.z; v[15]=a3.w;
            v[16]=a4.x; v[17]=a4.y; v[18]=a4.z; v[19]=a4.w;
        }
        float sum = 0.f, wsum = 0.f;
        #pragma unroll
        for (int i = 0; i < WLEN; ++i){
            sum += v[i];
            wsum += v[i] * ((float)(i + 1) * (1.0f / 210.0f));
        }
        float mean = sum * (1.0f / WLEN);
        float var = 0.f, m3 = 0.f, m4 = 0.f;
        #pragma unroll
        for (int i = 0; i < WLEN; ++i){
            float c = v[i] - mean, c2 = c * c;
            var += c2; m3 += c2 * c; m4 += c2 * c2;
        }
        var *= 0.05f; m3 *= 0.05f; m4 *= 0.05f;
        float sd = sqrtf(var);
        float ratio = v[WLEN - 1] / (v[0] + 0.01f) - 1.0f;   // pre-sort order

        #pragma unroll
        for (int rr = 0; rr < 10; ++rr){
            #pragma unroll
            for (int i = (rr & 1); i + 1 < 10; i += 2){
                float lo0 = fminf(v[i], v[i + 1]);
                float hi0 = fmaxf(v[i], v[i + 1]);
                v[i] = lo0; v[i + 1] = hi0;
                float lo1 = fminf(v[10 + i], v[10 + i + 1]);
                float hi1 = fmaxf(v[10 + i], v[10 + i + 1]);
                v[10 + i] = lo1; v[10 + i + 1] = hi1;
            }
        }
        float Lmax = fminf(v[0], v[19]);
        float Hmin = fmaxf(v[0], v[19]);
        #pragma unroll
        for (int i = 1; i < 10; ++i){
            float li = fminf(v[i], v[19 - i]);
            float hi2 = fmaxf(v[i], v[19 - i]);
            Lmax = fmaxf(Lmax, li);
            Hmin = fminf(Hmin, hi2);
        }
        float median = 0.5f * (Lmax + Hmin);
        float minv = fminf(v[0], v[10]);
        float s3 = sd * sd * sd;
        float mos = mean / (sd + 0.01f);
        float skew = m3 / (s3 + 0.01f);
        float kurt = m4 / (s3 * sd + 0.01f) - 3.0f;

        ts[t][  0 + f] = sd;
        ts[t][ 10 + f] = mos;
        ts[t][ 20 + f] = ratio;
        ts[t][ 30 + f] = wsum;
        ts[t][ 40 + f] = mean;
        ts[t][ 50 + f] = minv;
        ts[t][ 60 + f] = var;
        ts[t][ 70 + f] = sum;
        ts[t][ 80 + f] = median;
        ts[t][ 90 + f] = skew;
        ts[t][100 + f] = kurt;
        ts[t][110 + f] = sum;
    }
    __syncthreads();   // S2: ts complete

    size_t grp = b >> 4, e = b & 15;

    // ---- pairs: Gram MFMA + inline cov/corr + direct feat32 writes ----
    {
        int w = tid >> 6, l = tid & 63;
        int f = l & 15, kb = l >> 4;
        float cs = 0.f, cq = 0.f, vs2 = 0.f, vq = 0.f;
        #pragma unroll 1
        for (int s = 0; s < 6; ++s){
            int nw = w * 6 + s;
            float vv[8];
            #pragma unroll
            for (int j = 0; j < 8; ++j) vv[j] = 0.f;
            if (f < NF && kb < 3){
                const float* p = &xs[f * XROW + nw * WLEN + kb * 8];
                float4 u0 = *(const float4*)p;
                vv[0] = u0.x; vv[1] = u0.y; vv[2] = u0.z; vv[3] = u0.w;
                if (kb < 2){
                    float4 u1 = *(const float4*)(p + 4);
                    vv[4] = u1.x; vv[5] = u1.y; vv[6] = u1.z; vv[7] = u1.w;
                }
            }
            bf16x8 Fh, Fl;
            #pragma unroll
            for (int j = 0; j < 8; ++j){ short hi, lo; split2(vv[j], hi, lo); Fh[j] = hi; Fl[j] = lo; }
            f32x4 g = {0.f, 0.f, 0.f, 0.f};
            g = MFMA(Fh, Fh, g);
            g = MFMA(Fh, Fl, g);
            g = MFMA(Fl, Fh, g);
            size_t base = ((grp * NWIN + nw) * 16 + e) * FROW;
            #pragma unroll
            for (int i = 0; i < 4; ++i){
                int fa = kb * 4 + i, fb = f;
                if (fa < fb && fb < NF){
                    float ma = ts[nw][40 + fa], mb = ts[nw][40 + fb];
                    float sa = ts[nw][0 + fa],  sb = ts[nw][0 + fb];
                    float cov = (g[i] - (float)WLEN * ma * mb) * (1.0f / (WLEN - 1));
                    float corr = cov / (sa * sb + 0.01f);
                    int pi = (((19 - fa) * fa) >> 1) + fb - fa - 1;
                    feat32[base + pi] = corr;
                    feat32[base + NPAIR + pi] = cov;
                    cs += corr; cq += corr * corr;
                    vs2 += cov; vq += cov * cov;
                }
            }
        }
        float acc[4] = {cs, cq, vs2, vq};
        int wid = b * 4 + w;
        #pragma unroll
        for (int j = 0; j < 4; ++j){
            float a = acc[j];
            #pragma unroll
            for (int m = 1; m < 64; m <<= 1) a += __shfl_xor(a, m);
            if (l == 0) part2[(size_t)j * NW2 + wid] = a;
        }
    }

    // ---- BN groups 2..13 via column owners ----
    if (tid < 120){
        int g = 2 + tid / 10;
        float s = 0.f, q = 0.f;
        #pragma unroll
        for (int t = 0; t < NWIN; ++t){
            float v = ts[t][tid];
            s += v; q += v * v;
        }
        atomicAdd(&sgs[g], s);
        atomicAdd(&sgq[g], q);
    }
    __syncthreads();   // S3

    if (tid < 24){
        int j = tid >> 1, wh = tid & 1;
        part1[(size_t)tid * NB + b] = wh ? sgq[2 + j] : sgs[2 + j];
    }
    for (int q = tid; q < NWIN * 120; q += 256){
        int t = q / 120, c = q % 120;
        size_t base = ((grp * NWIN + t) * 16 + e) * FROW;
        feat32[base + 90 + c] = ts[t][c];
    }
    if (tid < 48){
        int t = tid >> 1;
        size_t base = ((grp * NWIN + t) * 16 + e) * FROW;
        feat32[base + 210 + (tid & 1)] = 0.f;
    }
}

// ---------------------------------------------------------------------------
// reduceA (unchanged)
// ---------------------------------------------------------------------------
__global__ __launch_bounds__(256)
void reduce_kernel(const float* __restrict__ part1, const float* __restrict__ part2,
                   float* __restrict__ accum)
{
    __shared__ float red[256];
    int j = blockIdx.x;
    int g = j % NG, which = j / NG;
    const float* base; int n;
    if (g < 2){ base = part2 + (size_t)(g * 2 + which) * NW2; n = NW2; }
    else      { base = part1 + (size_t)((g - 2) * 2 + which) * NB; n = NB; }
    int tid = threadIdx.x;
    float s = 0.f;
    for (int i = tid; i < n; i += 256) s += base[i];
    red[tid] = s; __syncthreads();
    for (int step = 128; step > 0; step >>= 1){
        if (tid < step) red[tid] += red[tid + step];
        __syncthreads();
    }
    if (tid == 0) accum[which * NG + g] = red[0];
}

// ---------------------------------------------------------------------------
// prep (unchanged)
// ---------------------------------------------------------------------------
__global__ __launch_bounds__(256)
void prep_kernel(const float* __restrict__ Wih0, const float* __restrict__ Whh0,
                 const float* __restrict__ Wih1, const float* __restrict__ Whh1,
                 const float* __restrict__ bih0, const float* __restrict__ accum,
                 const float* __restrict__ conv_w, const float* __restrict__ bn_gamma,
                 const float* __restrict__ bn_beta,
                 short* __restrict__ WHh, short* __restrict__ W0h, float* __restrict__ bf0)
{
    __shared__ float scs[NG], shs[NG];
    int tid = threadIdx.x;
    if (tid < NG){
        float N = (tid < 2) ? 4096.f * NPAIR * NWIN : 4096.f * NF * NWIN;
        float m = accum[tid] / N;
        float v = accum[NG + tid] / N - m * m;
        float cw = conv_w[0];
        float A = bn_gamma[tid] * rsqrtf(cw * cw * v + 1e-5f);
        scs[tid] = A * cw;
        shs[tid] = bn_beta[tid] - A * cw * m;
    }
    __syncthreads();
    const int NH = 3 * 2 * 12 * 64 * 8;
    const int N0 = 7 * 12 * 64 * 8;
    for (int i = blockIdx.x * 256 + tid; i < NH + N0; i += gridDim.x * 256){
        if (i < NH){
            int j = i & 7, lane = (i >> 3) & 63, rest = i >> 9;
            int ct = rest % 12; rest /= 12;
            int ks = rest & 1, m = rest >> 1;
            int gg = ct * 16 + (lane & 15);
            int k = ks * 32 + ((lane >> 4) << 3) + j;
            const float* Wm = (m == 0) ? Whh0 : (m == 1) ? Wih1 : Whh1;
            WHh[i] = bf16rne(Wm[gg * HID + k]);
        } else {
            int e2 = i - NH;
            int j = e2 & 7, lane = (e2 >> 3) & 63, rest = e2 >> 9;
            int ct = rest % 12, ks = rest / 12;
            int gg = ct * 16 + (lane & 15);
            int k = ks * 32 + ((lane >> 4) << 3) + j;
            float v = (k < DIN) ? Wih0[gg * DIN + k] * scs[grp_of(k)] : 0.f;
            W0h[e2] = bf16rne(v);
        }
    }
    if (blockIdx.x == 0 && tid < GATES){
        float s = bih0[tid];
        for (int k = 0; k < DIN; ++k) s += Wih0[tid * DIN + k] * shs[grp_of(k)];
        bf0[tid] = s;
    }
}

// ---------------------------------------------------------------------------
// rec v6: 512 blocks x 8 batch rows (16-row MFMA fragment, rows 8-15 carry
// bounded junk that never leaves rows 8-15) -> 2 blocks/CU overlap.
// Same 2-stage layer pipeline + T14 split staging as v5; per-tile staging
// halves to 216 chunks (1 chunk/B-thread). fa zero slots init'd once.
// ---------------------------------------------------------------------------
__global__ __launch_bounds__(512, 4)
void rec_kernel(const float* __restrict__ feat32,
                const short* __restrict__ WHh, const short* __restrict__ W0h,
                const float* __restrict__ bf0, const float* __restrict__ bhh0,
                const float* __restrict__ bih1, const float* __restrict__ bhh1,
                float* __restrict__ out)
{
    __shared__ __align__(16) short fa[2][14][64][8];     // 28.7 KB
    __shared__ __align__(16) short hp0[2][2][16][72];    // 9.2 KB
    __shared__ __align__(16) short hp1[2][2][16][72];    // 9.2 KB
    int tid = threadIdx.x;
    int w = tid >> 6, l = tid & 63;
    int lm = l & 15, kb = l >> 4;
    int blk = blockIdx.x;
    size_t grp = blk >> 1;
    int ebase = (blk & 1) * 8;

    // zero everything once (fa junk slots stay zero forever)
    for (int i = tid; i < 2 * 2 * 16 * 72; i += 512){
        ((short*)hp0)[i] = 0;
        ((short*)hp1)[i] = 0;
    }
    for (int i = tid; i < 2 * 14 * 64 * 8; i += 512) ((short*)fa)[i] = 0;
    __syncthreads();   // Z0

    // stage tile 0 into fa[0] (216 chunks, all 512 threads)
    if (tid < 216){
        int e8 = tid / 27, c = tid % 27;
        const float* srcp = &feat32[((grp * NWIN + 0) * 16 + ebase + e8) * FROW + c * 8];
        float vv[8];
        if (c < 26){
            float4 u0 = *(const float4*)srcp, u1 = *(const float4*)(srcp + 4);
            vv[0]=u0.x; vv[1]=u0.y; vv[2]=u0.z; vv[3]=u0.w;
            vv[4]=u1.x; vv[5]=u1.y; vv[6]=u1.z; vv[7]=u1.w;
        } else {
            float4 u0 = *(const float4*)srcp;
            vv[0]=u0.x; vv[1]=u0.y; vv[2]=u0.z; vv[3]=u0.w;
            vv[4]=0.f; vv[5]=0.f; vv[6]=0.f; vv[7]=0.f;
        }
        bf16x8 h8, l8;
        #pragma unroll
        for (int j = 0; j < 8; ++j){ short hi, lo; split2(vv[j], hi, lo); h8[j] = hi; l8[j] = lo; }
        *(bf16x8*)&fa[0][(c >> 2) * 2 + 0][e8 + 16 * (c & 3)][0] = h8;
        *(bf16x8*)&fa[0][(c >> 2) * 2 + 1][e8 + 16 * (c & 3)][0] = l8;
    }

    if (w < 4){
        // =================== group A: layer 0 ===================
        int jc = w * 16 + lm;
        bf16x8 WH0_[2][3];
        #pragma unroll
        for (int ks = 0; ks < 2; ++ks)
            #pragma unroll
            for (int ro = 0; ro < 3; ++ro)
                WH0_[ks][ro] = *(const bf16x8*)&WHh[((((0 * 2 + ks) * 12) + (ro * 4 + w)) * 64 + l) * 8];
        bf16x8 W0_[7][3];
        #pragma unroll
        for (int ks = 0; ks < 7; ++ks)
            #pragma unroll
            for (int ro = 0; ro < 3; ++ro)
                W0_[ks][ro] = *(const bf16x8*)&W0h[(((ks * 12) + (ro * 4 + w)) * 64 + l) * 8];

        float cr0 = bf0[jc]       + bhh0[jc];
        float cz0 = bf0[jc + 64]  + bhh0[jc + 64];
        float cin0 = bf0[jc + 128];
        float chn0 = bhh0[jc + 128];
        float h0p[4] = {0.f, 0.f, 0.f, 0.f};

        __syncthreads();   // P0
        #pragma unroll 1
        for (int k = 0; k < 25; ++k){
            if (k < 24){
                int rb = (k & 1) ^ 1, wb = k & 1;
                bf16x8 h0h[2], h0l[2];
                #pragma unroll
                for (int ks = 0; ks < 2; ++ks){
                    int off = ks * 32 + kb * 8;
                    h0h[ks] = *(const bf16x8*)&hp0[rb][0][lm][off];
                    h0l[ks] = *(const bf16x8*)&hp0[rb][1][lm][off];
                }
                f32x4 ar0 = {cr0, cr0, cr0, cr0};
                f32x4 az0 = {cz0, cz0, cz0, cz0};
                f32x4 ain0 = {cin0, cin0, cin0, cin0};
                f32x4 ahn0 = {chn0, chn0, chn0, chn0};
                #pragma unroll
                for (int ks = 0; ks < 2; ++ks){
                    ar0 = MFMA(h0h[ks], WH0_[ks][0], ar0);  ar0 = MFMA(h0l[ks], WH0_[ks][0], ar0);
                    az0 = MFMA(h0h[ks], WH0_[ks][1], az0);  az0 = MFMA(h0l[ks], WH0_[ks][1], az0);
                    ahn0 = MFMA(h0h[ks], WH0_[ks][2], ahn0); ahn0 = MFMA(h0l[ks], WH0_[ks][2], ahn0);
                }
                #pragma unroll
                for (int ks = 0; ks < 7; ++ks){
                    bf16x8 Fh = *(const bf16x8*)&fa[k & 1][ks * 2 + 0][l][0];
                    bf16x8 Fl = *(const bf16x8*)&fa[k & 1][ks * 2 + 1][l][0];
                    ar0 = MFMA(Fh, W0_[ks][0], ar0);  ar0 = MFMA(Fl, W0_[ks][0], ar0);
                    az0 = MFMA(Fh, W0_[ks][1], az0);  az0 = MFMA(Fl, W0_[ks][1], az0);
                    ain0 = MFMA(Fh, W0_[ks][2], ain0); ain0 = MFMA(Fl, W0_[ks][2], ain0);
                }
                #pragma unroll
                for (int i = 0; i < 4; ++i){
                    int row = kb * 4 + i;
                    float rg = sigm(ar0[i]);
                    float zg = sigm(az0[i]);
                    float nn = tanhfast(ain0[i] + rg * ahn0[i]);
                    float h = (1.f - zg) * nn + zg * h0p[i];
                    h0p[i] = h;
                    short hi, lo; split2(h, hi, lo);
                    hp0[wb][0][row][jc] = hi;
                    hp0[wb][1][row][jc] = lo;
                }
            }
            __syncthreads();
        }
    } else {
        // =================== group B: layer 1 + split staging ===================
        int w2 = w - 4;
        int jc = w2 * 16 + lm;
        int ht = tid - 256;
        bf16x8 WH1_[2][3], WH2_[2][3];
        #pragma unroll
        for (int ks = 0; ks < 2; ++ks)
            #pragma unroll
            for (int ro = 0; ro < 3; ++ro){
                WH1_[ks][ro] = *(const bf16x8*)&WHh[((((1 * 2 + ks) * 12) + (ro * 4 + w2)) * 64 + l) * 8];
                WH2_[ks][ro] = *(const bf16x8*)&WHh[((((2 * 2 + ks) * 12) + (ro * 4 + w2)) * 64 + l) * 8];
            }
        float cr1 = bih1[jc]      + bhh1[jc];
        float cz1 = bih1[jc + 64] + bhh1[jc + 64];
        float cin1 = bih1[jc + 128];
        float chn1 = bhh1[jc + 128];
        float h1p[4] = {0.f, 0.f, 0.f, 0.f};

        int se8 = ht / 27, sc = ht % 27;     // this thread's staging chunk
        bool stg = (ht < 216);
        // prologue: load tile 1 into registers
        float4 pr0 = make_float4(0.f,0.f,0.f,0.f), pr1 = make_float4(0.f,0.f,0.f,0.f);
        if (stg){
            const float* srcp = &feat32[((grp * NWIN + 1) * 16 + ebase + se8) * FROW + sc * 8];
            if (sc < 26){ pr0 = *(const float4*)srcp; pr1 = *(const float4*)(srcp + 4); }
            else        { pr0 = *(const float4*)srcp; }
        }
        __syncthreads();   // P0

        #pragma unroll 1
        for (int k = 0; k < 25; ++k){
            // (a) write tile k+1 from regs
            if (k <= 22 && stg){
                short (*fab)[64][8] = fa[(k + 1) & 1];
                float vv[8] = {pr0.x, pr0.y, pr0.z, pr0.w, pr1.x, pr1.y, pr1.z, pr1.w};
                bf16x8 h8, l8;
                #pragma unroll
                for (int j = 0; j < 8; ++j){ short hi, lo; split2(vv[j], hi, lo); h8[j] = hi; l8[j] = lo; }
                *(bf16x8*)&fab[(sc >> 2) * 2 + 0][se8 + 16 * (sc & 3)][0] = h8;
                *(bf16x8*)&fab[(sc >> 2) * 2 + 1][se8 + 16 * (sc & 3)][0] = l8;
            }
            // (b) issue loads for tile k+2
            if (k <= 21 && stg){
                const float* srcp = &feat32[((grp * NWIN + k + 2) * 16 + ebase + se8) * FROW + sc * 8];
                pr1 = make_float4(0.f,0.f,0.f,0.f);
                if (sc < 26){ pr0 = *(const float4*)srcp; pr1 = *(const float4*)(srcp + 4); }
                else        { pr0 = *(const float4*)srcp; }
            }
            // (c) layer-1 compute for t = k-1
            if (k >= 1){
                int t = k - 1;
                int rb0 = t & 1;
                int rh = (k & 1) ^ 1, wh = k & 1;
                bf16x8 n0h[2], n0l[2], h1h[2], h1l[2];
                #pragma unroll
                for (int ks = 0; ks < 2; ++ks){
                    int off = ks * 32 + kb * 8;
                    n0h[ks] = *(const bf16x8*)&hp0[rb0][0][lm][off];
                    n0l[ks] = *(const bf16x8*)&hp0[rb0][1][lm][off];
                    h1h[ks] = *(const bf16x8*)&hp1[rh][0][lm][off];
                    h1l[ks] = *(const bf16x8*)&hp1[rh][1][lm][off];
                }
                f32x4 ar1 = {cr1, cr1, cr1, cr1};
                f32x4 az1 = {cz1, cz1, cz1, cz1};
                f32x4 ain1 = {cin1, cin1, cin1, cin1};
                f32x4 ahn1 = {chn1, chn1, chn1, chn1};
                #pragma unroll
                for (int ks = 0; ks < 2; ++ks){
                    ar1 = MFMA(n0h[ks], WH1_[ks][0], ar1);  ar1 = MFMA(n0l[ks], WH1_[ks][0], ar1);
                    az1 = MFMA(n0h[ks], WH1_[ks][1], az1);  az1 = MFMA(n0l[ks], WH1_[ks][1], az1);
                    ain1 = MFMA(n0h[ks], WH1_[ks][2], ain1); ain1 = MFMA(n0l[ks], WH1_[ks][2], ain1);
                    ar1 = MFMA(h1h[ks], WH2_[ks][0], ar1);  ar1 = MFMA(h1l[ks], WH2_[ks][0], ar1);
                    az1 = MFMA(h1h[ks], WH2_[ks][1], az1);  az1 = MFMA(h1l[ks], WH2_[ks][1], az1);
                    ahn1 = MFMA(h1h[ks], WH2_[ks][2], ahn1); ahn1 = MFMA(h1l[ks], WH2_[ks][2], ahn1);
                }
                #pragma unroll
                for (int i = 0; i < 4; ++i){
                    int row = kb * 4 + i;
                    float rg = sigm(ar1[i]);
                    float zg = sigm(az1[i]);
                    float nn = tanhfast(ain1[i] + rg * ahn1[i]);
                    float h = (1.f - zg) * nn + zg * h1p[i];
                    h1p[i] = h;
                    short hi, lo; split2(h, hi, lo);
                    hp1[wh][0][row][jc] = hi;
                    hp1[wh][1][row][jc] = lo;
                }
            }
            __syncthreads();
        }
        if (kb < 2){
            #pragma unroll
            for (int i = 0; i < 4; ++i)
                out[((size_t)(blk * 8) + kb * 4 + i) * HID + jc] = h1p[i];
        }
    }
}

// ---------------------------------------------------------------------------
extern "C" void kernel_launch(void* const* d_in, const int* in_sizes, int n_in,
                              void* d_out, int out_size, void* d_ws, size_t ws_size,
                              hipStream_t stream) {
    const float* data     = (const float*)d_in[0];
    const float* conv_w   = (const float*)d_in[1];
    const float* bn_gamma = (const float*)d_in[3];
    const float* bn_beta  = (const float*)d_in[4];
    const float* Wih0     = (const float*)d_in[5];
    const float* Whh0     = (const float*)d_in[6];
    const float* bih0     = (const float*)d_in[7];
    const float* bhh0     = (const float*)d_in[8];
    const float* Wih1     = (const float*)d_in[9];
    const float* Whh1     = (const float*)d_in[10];
    const float* bih1     = (const float*)d_in[11];
    const float* bhh1     = (const float*)d_in[12];
    float* out = (float*)d_out;

    char* ws = (char*)d_ws;
    const size_t feat32_bytes = (size_t)256 * NWIN * 16 * FROW * 4;    // 83,361,792
    const size_t WH_BYTES = 3 * 2 * 12 * 64 * 8 * 2;                    // 73,728
    const size_t W0_BYTES = 7 * 12 * 64 * 8 * 2;                        // 86,016
    const size_t P1_BYTES = (size_t)24 * NB * 4;                        // 393,216

    float* feat32 = (float*)ws;
    short* WHh  = (short*)(ws + feat32_bytes);
    short* W0h  = (short*)(ws + feat32_bytes + WH_BYTES);
    float* bf0  = (float*)(ws + feat32_bytes + WH_BYTES + W0_BYTES);
    float* accum = (float*)(ws + feat32_bytes + WH_BYTES + W0_BYTES + 1024);
    float* part1 = (float*)(ws + feat32_bytes + WH_BYTES + W0_BYTES + 2048);
    float* part2 = (float*)(ws + feat32_bytes + WH_BYTES + W0_BYTES + 2048 + P1_BYTES);

    stats_kernel<<<NB, 256, 0, stream>>>(data, feat32, part1, part2);
    reduce_kernel<<<28, 256, 0, stream>>>(part1, part2, accum);
    prep_kernel<<<64, 256, 0, stream>>>(Wih0, Whh0, Wih1, Whh1, bih0, accum,
                                        conv_w, bn_gamma, bn_beta, WHh, W0h, bf0);
    rec_kernel<<<RBLK, 512, 0, stream>>>(feat32, WHh, W0h, bf0,
                                         bhh0, bih1, bhh1, out);
}

// Round 22
// 126.124 us; speedup vs baseline: 1.3954x; 1.3954x over previous
//
#include <hip/hip_runtime.h>
#include <math.h>

#define NF 10
#define TLEN 480
#define NWIN 24
#define WLEN 20
#define HID 64
#define NPAIR 45
#define DIN 210
#define NG 14
#define GATES 192
#define NGRP 256            // 4096 / 16 rows per group
#define FROW 212            // fp32 feat row length (53 float4)
#define XROW 484            // padded LDS row
#define NB 4096             // stats blocks (one per batch element)
#define NW2 16384

typedef __attribute__((ext_vector_type(8))) short bf16x8;
typedef __attribute__((ext_vector_type(4))) float f32x4;

#define MFMA(a,b,c) __builtin_amdgcn_mfma_f32_16x16x32_bf16((a),(b),(c),0,0,0)

__device__ __forceinline__ int grp_of(int k){ return (k < 90) ? (k / 45) : 2 + (k - 90) / 10; }

__device__ __forceinline__ void split2(float x, short& hi, short& lo){
    unsigned u = __float_as_uint(x);
    hi = (short)(u >> 16);
    float hf = __uint_as_float(u & 0xffff0000u);
    lo = (short)(__float_as_uint(x - hf) >> 16);
}
__device__ __forceinline__ short bf16rne(float x){
    unsigned u = __float_as_uint(x);
    u += 0x7fffu + ((u >> 16) & 1u);
    return (short)(u >> 16);
}
__device__ __forceinline__ float sigm(float x){
    return __builtin_amdgcn_rcpf(1.f + __builtin_amdgcn_exp2f(x * -1.4426950408889634f));
}
__device__ __forceinline__ float tanhfast(float x){
    return 1.f - 2.f * __builtin_amdgcn_rcpf(1.f + __builtin_amdgcn_exp2f(x * 2.8853900817779268f));
}

// ---------------------------------------------------------------------------
// stats v9 (R18/R20 configuration, best measured ~70us)
// ---------------------------------------------------------------------------
__global__ __launch_bounds__(256)
void stats_kernel(const float* __restrict__ data, float* __restrict__ feat32,
                  float* __restrict__ part1, float* __restrict__ part2)
{
    __shared__ __align__(16) float xs[NF * XROW];   // 19.36 KB
    __shared__ float ts[NWIN][121];                 // 11.6 KB  (col j*10+f)
    __shared__ float sgs[NG], sgq[NG];
    int b = blockIdx.x, tid = threadIdx.x;
    const float* src = data + (size_t)b * (NF * TLEN);

    for (int q = tid; q < 1200; q += 256){
        int f = q / 120, r = q % 120;
        *(float4*)&xs[f * XROW + r * 4] = *(const float4*)&src[q * 4];
    }
    if (tid < NG){ sgs[tid] = 0.f; sgq[tid] = 0.f; }
    __syncthreads();   // S1: xs staged

    // ---- singles ----
    if (tid < 240){
        int f = tid / NWIN, t = tid % NWIN;
        const float* p = &xs[f * XROW + t * WLEN];
        float v[WLEN];
        {
            float4 a0 = *(const float4*)(p + 0);
            float4 a1 = *(const float4*)(p + 4);
            float4 a2 = *(const float4*)(p + 8);
            float4 a3 = *(const float4*)(p + 12);
            float4 a4 = *(const float4*)(p + 16);
            v[0]=a0.x; v[1]=a0.y; v[2]=a0.z; v[3]=a0.w;
            v[4]=a1.x; v[5]=a1.y; v[6]=a1.z; v[7]=a1.w;
            v[8]=a2.x; v[9]=a2.y; v[10]=a2.z; v[11]=a2.w;
            v[12]=a3.x; v[13]=a3.y; v[14]=a3.z; v[15]=a3.w;
            v[16]=a4.x; v[17]=a4.y; v[18]=a4.z; v[19]=a4.w;
        }
        float sum = 0.f, wsum = 0.f;
        #pragma unroll
        for (int i = 0; i < WLEN; ++i){
            sum += v[i];
            wsum += v[i] * ((float)(i + 1) * (1.0f / 210.0f));
        }
        float mean = sum * (1.0f / WLEN);
        float var = 0.f, m3 = 0.f, m4 = 0.f;
        #pragma unroll
        for (int i = 0; i < WLEN; ++i){
            float c = v[i] - mean, c2 = c * c;
            var += c2; m3 += c2 * c; m4 += c2 * c2;
        }
        var *= 0.05f; m3 *= 0.05f; m4 *= 0.05f;
        float sd = sqrtf(var);
        float ratio = v[WLEN - 1] / (v[0] + 0.01f) - 1.0f;   // pre-sort order

        #pragma unroll
        for (int rr = 0; rr < 10; ++rr){
            #pragma unroll
            for (int i = (rr & 1); i + 1 < 10; i += 2){
                float lo0 = fminf(v[i], v[i + 1]);
                float hi0 = fmaxf(v[i], v[i + 1]);
                v[i] = lo0; v[i + 1] = hi0;
                float lo1 = fminf(v[10 + i], v[10 + i + 1]);
                float hi1 = fmaxf(v[10 + i], v[10 + i + 1]);
                v[10 + i] = lo1; v[10 + i + 1] = hi1;
            }
        }
        float Lmax = fminf(v[0], v[19]);
        float Hmin = fmaxf(v[0], v[19]);
        #pragma unroll
        for (int i = 1; i < 10; ++i){
            float li = fminf(v[i], v[19 - i]);
            float hi2 = fmaxf(v[i], v[19 - i]);
            Lmax = fmaxf(Lmax, li);
            Hmin = fminf(Hmin, hi2);
        }
        float median = 0.5f * (Lmax + Hmin);
        float minv = fminf(v[0], v[10]);
        float s3 = sd * sd * sd;
        float mos = mean / (sd + 0.01f);
        float skew = m3 / (s3 + 0.01f);
        float kurt = m4 / (s3 * sd + 0.01f) - 3.0f;

        ts[t][  0 + f] = sd;
        ts[t][ 10 + f] = mos;
        ts[t][ 20 + f] = ratio;
        ts[t][ 30 + f] = wsum;
        ts[t][ 40 + f] = mean;
        ts[t][ 50 + f] = minv;
        ts[t][ 60 + f] = var;
        ts[t][ 70 + f] = sum;
        ts[t][ 80 + f] = median;
        ts[t][ 90 + f] = skew;
        ts[t][100 + f] = kurt;
        ts[t][110 + f] = sum;
    }
    __syncthreads();   // S2: ts complete

    size_t grp = b >> 4, e = b & 15;

    // ---- pairs: Gram MFMA + inline cov/corr + direct feat32 writes ----
    {
        int w = tid >> 6, l = tid & 63;
        int f = l & 15, kb = l >> 4;
        float cs = 0.f, cq = 0.f, vs2 = 0.f, vq = 0.f;
        #pragma unroll 1
        for (int s = 0; s < 6; ++s){
            int nw = w * 6 + s;
            float vv[8];
            #pragma unroll
            for (int j = 0; j < 8; ++j) vv[j] = 0.f;
            if (f < NF && kb < 3){
                const float* p = &xs[f * XROW + nw * WLEN + kb * 8];
                float4 u0 = *(const float4*)p;
                vv[0] = u0.x; vv[1] = u0.y; vv[2] = u0.z; vv[3] = u0.w;
                if (kb < 2){
                    float4 u1 = *(const float4*)(p + 4);
                    vv[4] = u1.x; vv[5] = u1.y; vv[6] = u1.z; vv[7] = u1.w;
                }
            }
            bf16x8 Fh, Fl;
            #pragma unroll
            for (int j = 0; j < 8; ++j){ short hi, lo; split2(vv[j], hi, lo); Fh[j] = hi; Fl[j] = lo; }
            f32x4 g = {0.f, 0.f, 0.f, 0.f};
            g = MFMA(Fh, Fh, g);
            g = MFMA(Fh, Fl, g);
            g = MFMA(Fl, Fh, g);
            size_t base = ((grp * NWIN + nw) * 16 + e) * FROW;
            #pragma unroll
            for (int i = 0; i < 4; ++i){
                int fa = kb * 4 + i, fb = f;
                if (fa < fb && fb < NF){
                    float ma = ts[nw][40 + fa], mb = ts[nw][40 + fb];
                    float sa = ts[nw][0 + fa],  sb = ts[nw][0 + fb];
                    float cov = (g[i] - (float)WLEN * ma * mb) * (1.0f / (WLEN - 1));
                    float corr = cov / (sa * sb + 0.01f);
                    int pi = (((19 - fa) * fa) >> 1) + fb - fa - 1;
                    feat32[base + pi] = corr;
                    feat32[base + NPAIR + pi] = cov;
                    cs += corr; cq += corr * corr;
                    vs2 += cov; vq += cov * cov;
                }
            }
        }
        float acc[4] = {cs, cq, vs2, vq};
        int wid = b * 4 + w;
        #pragma unroll
        for (int j = 0; j < 4; ++j){
            float a = acc[j];
            #pragma unroll
            for (int m = 1; m < 64; m <<= 1) a += __shfl_xor(a, m);
            if (l == 0) part2[(size_t)j * NW2 + wid] = a;
        }
    }

    // ---- BN groups 2..13 via column owners ----
    if (tid < 120){
        int g = 2 + tid / 10;
        float s = 0.f, q = 0.f;
        #pragma unroll
        for (int t = 0; t < NWIN; ++t){
            float v = ts[t][tid];
            s += v; q += v * v;
        }
        atomicAdd(&sgs[g], s);
        atomicAdd(&sgq[g], q);
    }
    __syncthreads();   // S3

    if (tid < 24){
        int j = tid >> 1, wh = tid & 1;
        part1[(size_t)tid * NB + b] = wh ? sgq[2 + j] : sgs[2 + j];
    }
    for (int q = tid; q < NWIN * 120; q += 256){
        int t = q / 120, c = q % 120;
        size_t base = ((grp * NWIN + t) * 16 + e) * FROW;
        feat32[base + 90 + c] = ts[t][c];
    }
    if (tid < 48){
        int t = tid >> 1;
        size_t base = ((grp * NWIN + t) * 16 + e) * FROW;
        feat32[base + 210 + (tid & 1)] = 0.f;
    }
}

// ---------------------------------------------------------------------------
// reduceA: part1 = [24][NB]; part2 = [4][NW2].
// ---------------------------------------------------------------------------
__global__ __launch_bounds__(256)
void reduce_kernel(const float* __restrict__ part1, const float* __restrict__ part2,
                   float* __restrict__ accum)
{
    __shared__ float red[256];
    int j = blockIdx.x;            // 0..27
    int g = j % NG, which = j / NG;
    const float* base; int n;
    if (g < 2){ base = part2 + (size_t)(g * 2 + which) * NW2; n = NW2; }
    else      { base = part1 + (size_t)((g - 2) * 2 + which) * NB; n = NB; }
    int tid = threadIdx.x;
    float s = 0.f;
    for (int i = tid; i < n; i += 256) s += base[i];
    red[tid] = s; __syncthreads();
    for (int step = 128; step > 0; step >>= 1){
        if (tid < step) red[tid] += red[tid + step];
        __syncthreads();
    }
    if (tid == 0) accum[which * NG + g] = red[0];
}

// ---------------------------------------------------------------------------
// prep (unchanged)
// ---------------------------------------------------------------------------
__global__ __launch_bounds__(256)
void prep_kernel(const float* __restrict__ Wih0, const float* __restrict__ Whh0,
                 const float* __restrict__ Wih1, const float* __restrict__ Whh1,
                 const float* __restrict__ bih0, const float* __restrict__ accum,
                 const float* __restrict__ conv_w, const float* __restrict__ bn_gamma,
                 const float* __restrict__ bn_beta,
                 short* __restrict__ WHh, short* __restrict__ W0h, float* __restrict__ bf0)
{
    __shared__ float scs[NG], shs[NG];
    int tid = threadIdx.x;
    if (tid < NG){
        float N = (tid < 2) ? 4096.f * NPAIR * NWIN : 4096.f * NF * NWIN;
        float m = accum[tid] / N;
        float v = accum[NG + tid] / N - m * m;
        float cw = conv_w[0];
        float A = bn_gamma[tid] * rsqrtf(cw * cw * v + 1e-5f);
        scs[tid] = A * cw;
        shs[tid] = bn_beta[tid] - A * cw * m;
    }
    __syncthreads();
    const int NH = 3 * 2 * 12 * 64 * 8;
    const int N0 = 7 * 12 * 64 * 8;
    for (int i = blockIdx.x * 256 + tid; i < NH + N0; i += gridDim.x * 256){
        if (i < NH){
            int j = i & 7, lane = (i >> 3) & 63, rest = i >> 9;
            int ct = rest % 12; rest /= 12;
            int ks = rest & 1, m = rest >> 1;
            int gg = ct * 16 + (lane & 15);
            int k = ks * 32 + ((lane >> 4) << 3) + j;
            const float* Wm = (m == 0) ? Whh0 : (m == 1) ? Wih1 : Whh1;
            WHh[i] = bf16rne(Wm[gg * HID + k]);
        } else {
            int e2 = i - NH;
            int j = e2 & 7, lane = (e2 >> 3) & 63, rest = e2 >> 9;
            int ct = rest % 12, ks = rest / 12;
            int gg = ct * 16 + (lane & 15);
            int k = ks * 32 + ((lane >> 4) << 3) + j;
            float v = (k < DIN) ? Wih0[gg * DIN + k] * scs[grp_of(k)] : 0.f;
            W0h[e2] = bf16rne(v);
        }
    }
    if (blockIdx.x == 0 && tid < GATES){
        float s = bih0[tid];
        for (int k = 0; k < DIN; ++k) s += Wih0[tid * DIN + k] * shs[grp_of(k)];
        bf0[tid] = s;
    }
}

// ---------------------------------------------------------------------------
// rec v5 (R20 configuration): 2-stage layer pipeline + T14 split staging.
// ---------------------------------------------------------------------------
__global__ __launch_bounds__(512, 1)
void rec_kernel(const float* __restrict__ feat32,
                const short* __restrict__ WHh, const short* __restrict__ W0h,
                const float* __restrict__ bf0, const float* __restrict__ bhh0,
                const float* __restrict__ bih1, const float* __restrict__ bhh1,
                float* __restrict__ out)
{
    __shared__ __align__(16) short fa[2][14][64][8];     // 28.7 KB
    __shared__ __align__(16) short hp0[2][2][16][72];    // 9.2 KB
    __shared__ __align__(16) short hp1[2][2][16][72];    // 9.2 KB
    int tid = threadIdx.x;
    int w = tid >> 6, l = tid & 63;
    int lm = l & 15, kb = l >> 4;
    int blk = blockIdx.x;

    for (int i = tid; i < 2 * 2 * 16 * 72; i += 512){
        ((short*)hp0)[i] = 0;
        ((short*)hp1)[i] = 0;
    }
    for (int q = tid; q < 448; q += 512){
        int c = q >> 4, e = q & 15;
        float vv[8];
        const float* src = &feat32[((size_t)(blk * NWIN) * 16 + e) * FROW + c * 8];
        if (c < 26){
            float4 u0 = *(const float4*)src, u1 = *(const float4*)(src + 4);
            vv[0]=u0.x; vv[1]=u0.y; vv[2]=u0.z; vv[3]=u0.w;
            vv[4]=u1.x; vv[5]=u1.y; vv[6]=u1.z; vv[7]=u1.w;
        } else if (c == 26){
            float4 u0 = *(const float4*)src;
            vv[0]=u0.x; vv[1]=u0.y; vv[2]=u0.z; vv[3]=u0.w;
            vv[4]=0.f; vv[5]=0.f; vv[6]=0.f; vv[7]=0.f;
        } else {
            #pragma unroll
            for (int j = 0; j < 8; ++j) vv[j] = 0.f;
        }
        bf16x8 h8, l8;
        #pragma unroll
        for (int j = 0; j < 8; ++j){ short hi, lo; split2(vv[j], hi, lo); h8[j] = hi; l8[j] = lo; }
        *(bf16x8*)&fa[0][(c >> 2) * 2 + 0][e + 16 * (c & 3)][0] = h8;
        *(bf16x8*)&fa[0][(c >> 2) * 2 + 1][e + 16 * (c & 3)][0] = l8;
    }

    if (w < 4){
        // =================== group A: layer 0 ===================
        int jc = w * 16 + lm;
        bf16x8 WH0_[2][3];
        #pragma unroll
        for (int ks = 0; ks < 2; ++ks)
            #pragma unroll
            for (int ro = 0; ro < 3; ++ro)
                WH0_[ks][ro] = *(const bf16x8*)&WHh[((((0 * 2 + ks) * 12) + (ro * 4 + w)) * 64 + l) * 8];
        bf16x8 W0_[7][3];
        #pragma unroll
        for (int ks = 0; ks < 7; ++ks)
            #pragma unroll
            for (int ro = 0; ro < 3; ++ro)
                W0_[ks][ro] = *(const bf16x8*)&W0h[(((ks * 12) + (ro * 4 + w)) * 64 + l) * 8];

        float cr0 = bf0[jc]       + bhh0[jc];
        float cz0 = bf0[jc + 64]  + bhh0[jc + 64];
        float cin0 = bf0[jc + 128];
        float chn0 = bhh0[jc + 128];
        float h0p[4] = {0.f, 0.f, 0.f, 0.f};

        __syncthreads();   // P0
        #pragma unroll 1
        for (int k = 0; k < 25; ++k){
            if (k < 24){
                int rb = (k & 1) ^ 1, wb = k & 1;
                bf16x8 h0h[2], h0l[2];
                #pragma unroll
                for (int ks = 0; ks < 2; ++ks){
                    int off = ks * 32 + kb * 8;
                    h0h[ks] = *(const bf16x8*)&hp0[rb][0][lm][off];
                    h0l[ks] = *(const bf16x8*)&hp0[rb][1][lm][off];
                }
                f32x4 ar0 = {cr0, cr0, cr0, cr0};
                f32x4 az0 = {cz0, cz0, cz0, cz0};
                f32x4 ain0 = {cin0, cin0, cin0, cin0};
                f32x4 ahn0 = {chn0, chn0, chn0, chn0};
                #pragma unroll
                for (int ks = 0; ks < 2; ++ks){
                    ar0 = MFMA(h0h[ks], WH0_[ks][0], ar0);  ar0 = MFMA(h0l[ks], WH0_[ks][0], ar0);
                    az0 = MFMA(h0h[ks], WH0_[ks][1], az0);  az0 = MFMA(h0l[ks], WH0_[ks][1], az0);
                    ahn0 = MFMA(h0h[ks], WH0_[ks][2], ahn0); ahn0 = MFMA(h0l[ks], WH0_[ks][2], ahn0);
                }
                #pragma unroll
                for (int ks = 0; ks < 7; ++ks){
                    bf16x8 Fh = *(const bf16x8*)&fa[k & 1][ks * 2 + 0][l][0];
                    bf16x8 Fl = *(const bf16x8*)&fa[k & 1][ks * 2 + 1][l][0];
                    ar0 = MFMA(Fh, W0_[ks][0], ar0);  ar0 = MFMA(Fl, W0_[ks][0], ar0);
                    az0 = MFMA(Fh, W0_[ks][1], az0);  az0 = MFMA(Fl, W0_[ks][1], az0);
                    ain0 = MFMA(Fh, W0_[ks][2], ain0); ain0 = MFMA(Fl, W0_[ks][2], ain0);
                }
                #pragma unroll
                for (int i = 0; i < 4; ++i){
                    int row = kb * 4 + i;
                    float rg = sigm(ar0[i]);
                    float zg = sigm(az0[i]);
                    float nn = tanhfast(ain0[i] + rg * ahn0[i]);
                    float h = (1.f - zg) * nn + zg * h0p[i];
                    h0p[i] = h;
                    short hi, lo; split2(h, hi, lo);
                    hp0[wb][0][row][jc] = hi;
                    hp0[wb][1][row][jc] = lo;
                }
            }
            __syncthreads();
        }
    } else {
        // =================== group B: layer 1 + split staging ===================
        int w2 = w - 4;
        int jc = w2 * 16 + lm;
        int ht = tid - 256;
        bf16x8 WH1_[2][3], WH2_[2][3];
        #pragma unroll
        for (int ks = 0; ks < 2; ++ks)
            #pragma unroll
            for (int ro = 0; ro < 3; ++ro){
                WH1_[ks][ro] = *(const bf16x8*)&WHh[((((1 * 2 + ks) * 12) + (ro * 4 + w2)) * 64 + l) * 8];
                WH2_[ks][ro] = *(const bf16x8*)&WHh[((((2 * 2 + ks) * 12) + (ro * 4 + w2)) * 64 + l) * 8];
            }
        float cr1 = bih1[jc]      + bhh1[jc];
        float cz1 = bih1[jc + 64] + bhh1[jc + 64];
        float cin1 = bih1[jc + 128];
        float chn1 = bhh1[jc + 128];
        float h1p[4] = {0.f, 0.f, 0.f, 0.f};

        // prologue: load tile 1 into registers
        float4 pr0[2], pr1[2];
        #pragma unroll
        for (int m = 0; m < 2; ++m){
            int q = ht + m * 256;
            pr0[m] = make_float4(0.f, 0.f, 0.f, 0.f);
            pr1[m] = make_float4(0.f, 0.f, 0.f, 0.f);
            if (q < 448){
                int c = q >> 4, e = q & 15;
                const float* srcp = &feat32[((size_t)(blk * NWIN + 1) * 16 + e) * FROW + c * 8];
                if (c < 26){ pr0[m] = *(const float4*)srcp; pr1[m] = *(const float4*)(srcp + 4); }
                else if (c == 26){ pr0[m] = *(const float4*)srcp; }
            }
        }
        __syncthreads();   // P0

        #pragma unroll 1
        for (int k = 0; k < 25; ++k){
            // (a) write tile k+1 from regs (loads issued a full iteration ago)
            if (k <= 22){
                short (*fab)[64][8] = fa[(k + 1) & 1];
                #pragma unroll
                for (int m = 0; m < 2; ++m){
                    int q = ht + m * 256;
                    if (q < 448){
                        int c = q >> 4, e = q & 15;
                        float vv[8] = {pr0[m].x, pr0[m].y, pr0[m].z, pr0[m].w,
                                       pr1[m].x, pr1[m].y, pr1[m].z, pr1[m].w};
                        bf16x8 h8, l8;
                        #pragma unroll
                        for (int j = 0; j < 8; ++j){ short hi, lo; split2(vv[j], hi, lo); h8[j] = hi; l8[j] = lo; }
                        *(bf16x8*)&fab[(c >> 2) * 2 + 0][e + 16 * (c & 3)][0] = h8;
                        *(bf16x8*)&fab[(c >> 2) * 2 + 1][e + 16 * (c & 3)][0] = l8;
                    }
                }
            }
            // (b) issue loads for tile k+2 (drain under l1 + barrier + A's MFMA)
            if (k <= 21){
                #pragma unroll
                for (int m = 0; m < 2; ++m){
                    int q = ht + m * 256;
                    pr0[m] = make_float4(0.f, 0.f, 0.f, 0.f);
                    pr1[m] = make_float4(0.f, 0.f, 0.f, 0.f);
                    if (q < 448){
                        int c = q >> 4, e = q & 15;
                        const float* srcp = &feat32[((size_t)(blk * NWIN + k + 2) * 16 + e) * FROW + c * 8];
                        if (c < 26){ pr0[m] = *(const float4*)srcp; pr1[m] = *(const float4*)(srcp + 4); }
                        else if (c == 26){ pr0[m] = *(const float4*)srcp; }
                    }
                }
            }
            // (c) layer-1 compute for t = k-1
            if (k >= 1){
                int t = k - 1;
                int rb0 = t & 1;
                int rh = (k & 1) ^ 1, wh = k & 1;
                bf16x8 n0h[2], n0l[2], h1h[2], h1l[2];
                #pragma unroll
                for (int ks = 0; ks < 2; ++ks){
                    int off = ks * 32 + kb * 8;
                    n0h[ks] = *(const bf16x8*)&hp0[rb0][0][lm][off];
                    n0l[ks] = *(const bf16x8*)&hp0[rb0][1][lm][off];
                    h1h[ks] = *(const bf16x8*)&hp1[rh][0][lm][off];
                    h1l[ks] = *(const bf16x8*)&hp1[rh][1][lm][off];
                }
                f32x4 ar1 = {cr1, cr1, cr1, cr1};
                f32x4 az1 = {cz1, cz1, cz1, cz1};
                f32x4 ain1 = {cin1, cin1, cin1, cin1};
                f32x4 ahn1 = {chn1, chn1, chn1, chn1};
                #pragma unroll
                for (int ks = 0; ks < 2; ++ks){
                    ar1 = MFMA(n0h[ks], WH1_[ks][0], ar1);  ar1 = MFMA(n0l[ks], WH1_[ks][0], ar1);
                    az1 = MFMA(n0h[ks], WH1_[ks][1], az1);  az1 = MFMA(n0l[ks], WH1_[ks][1], az1);
                    ain1 = MFMA(n0h[ks], WH1_[ks][2], ain1); ain1 = MFMA(n0l[ks], WH1_[ks][2], ain1);
                    ar1 = MFMA(h1h[ks], WH2_[ks][0], ar1);  ar1 = MFMA(h1l[ks], WH2_[ks][0], ar1);
                    az1 = MFMA(h1h[ks], WH2_[ks][1], az1);  az1 = MFMA(h1l[ks], WH2_[ks][1], az1);
                    ahn1 = MFMA(h1h[ks], WH2_[ks][2], ahn1); ahn1 = MFMA(h1l[ks], WH2_[ks][2], ahn1);
                }
                #pragma unroll
                for (int i = 0; i < 4; ++i){
                    int row = kb * 4 + i;
                    float rg = sigm(ar1[i]);
                    float zg = sigm(az1[i]);
                    float nn = tanhfast(ain1[i] + rg * ahn1[i]);
                    float h = (1.f - zg) * nn + zg * h1p[i];
                    h1p[i] = h;
                    short hi, lo; split2(h, hi, lo);
                    hp1[wh][0][row][jc] = hi;
                    hp1[wh][1][row][jc] = lo;
                }
            }
            __syncthreads();
        }
        #pragma unroll
        for (int i = 0; i < 4; ++i)
            out[((size_t)(blk * 16) + kb * 4 + i) * HID + jc] = h1p[i];
    }
}

// ---------------------------------------------------------------------------
extern "C" void kernel_launch(void* const* d_in, const int* in_sizes, int n_in,
                              void* d_out, int out_size, void* d_ws, size_t ws_size,
                              hipStream_t stream) {
    const float* data     = (const float*)d_in[0];
    const float* conv_w   = (const float*)d_in[1];
    const float* bn_gamma = (const float*)d_in[3];
    const float* bn_beta  = (const float*)d_in[4];
    const float* Wih0     = (const float*)d_in[5];
    const float* Whh0     = (const float*)d_in[6];
    const float* bih0     = (const float*)d_in[7];
    const float* bhh0     = (const float*)d_in[8];
    const float* Wih1     = (const float*)d_in[9];
    const float* Whh1     = (const float*)d_in[10];
    const float* bih1     = (const float*)d_in[11];
    const float* bhh1     = (const float*)d_in[12];
    float* out = (float*)d_out;

    char* ws = (char*)d_ws;
    const size_t feat32_bytes = (size_t)NGRP * NWIN * 16 * FROW * 4;   // 83,361,792
    const size_t WH_BYTES = 3 * 2 * 12 * 64 * 8 * 2;                    // 73,728
    const size_t W0_BYTES = 7 * 12 * 64 * 8 * 2;                        // 86,016
    const size_t P1_BYTES = (size_t)24 * NB * 4;                        // 393,216

    float* feat32 = (float*)ws;
    short* WHh  = (short*)(ws + feat32_bytes);
    short* W0h  = (short*)(ws + feat32_bytes + WH_BYTES);
    float* bf0  = (float*)(ws + feat32_bytes + WH_BYTES + W0_BYTES);
    float* accum = (float*)(ws + feat32_bytes + WH_BYTES + W0_BYTES + 1024);
    float* part1 = (float*)(ws + feat32_bytes + WH_BYTES + W0_BYTES + 2048);
    float* part2 = (float*)(ws + feat32_bytes + WH_BYTES + W0_BYTES + 2048 + P1_BYTES);

    stats_kernel<<<NB, 256, 0, stream>>>(data, feat32, part1, part2);
    reduce_kernel<<<28, 256, 0, stream>>>(part1, part2, accum);
    prep_kernel<<<64, 256, 0, stream>>>(Wih0, Whh0, Wih1, Whh1, bih0, accum,
                                        conv_w, bn_gamma, bn_beta, WHh, W0h, bf0);
    rec_kernel<<<NGRP, 512, 0, stream>>>(feat32, WHh, W0h, bf0,
                                         bhh0, bih1, bhh1, out);
}